// Round 10
// baseline (655.882 us; speedup 1.0000x reference)
//
#include <hip/hip_runtime.h>
#include <math.h>

typedef unsigned short u16;
typedef unsigned int u32;
using bf16x8 = __attribute__((ext_vector_type(8))) short;
using f32x4  = __attribute__((ext_vector_type(4))) float;

#define DD 4096
#define NB 256            // batch
#define SPLIT_K 16
#define PSTRIDE (NB * DD) // elements per partial plane
#define PLANE (NB * DD)   // floats per transform layer plane

__device__ __forceinline__ u16 f2bf(float f) {
  unsigned int u = __float_as_uint(f);
  u += 0x7fffu + ((u >> 16) & 1u);   // RNE
  return (u16)(u >> 16);
}
__device__ __forceinline__ float bf2f(u16 h) {
  return __uint_as_float((u32)h << 16);
}
__device__ __forceinline__ unsigned int pack2bf(float a, float b) {
  return (unsigned int)f2bf(a) | ((unsigned int)f2bf(b) << 16);
}
__device__ __forceinline__ void async_cp16(const u16* g, u16* l) {
  __builtin_amdgcn_global_load_lds(
      (const __attribute__((address_space(1))) unsigned int*)g,
      (__attribute__((address_space(3))) unsigned int*)l, 16, 0, 0);
}

// ---------------------------------------------------------------------------
// GEMM: part[kz] = Xf(bf16) @ W^T over K-chunk kz (K=256), output bf16.
// grid (64 nt, 16 kz) = 1024 WGs = 4 WG/CU (40 KB LDS x4 = 160 KB; VGPR<=64
// via launch_bounds(512,8)) = 32 waves/CU. Max TLP hides the per-iter drain.
// ---------------------------------------------------------------------------
__global__ __launch_bounds__(512, 8) void gemm_kernel(
    const u16* __restrict__ A, const float* __restrict__ W,
    u16* __restrict__ part)
{
  const int nt = blockIdx.x;
  const int kz = blockIdx.y;
  const int t = threadIdx.x;
  const int w = t >> 6, l = t & 63;

  __shared__ __align__(16) u16 As[256 * 64];   // 32 KB
  __shared__ __align__(16) u16 Bs[64 * 64];    // 8 KB

  const int colg0 = nt << 6;
  const int k0 = kz << 8;                      // K-chunk of 256

  f32x4 acc[4][2];
#pragma unroll
  for (int mi = 0; mi < 4; ++mi)
#pragma unroll
    for (int nj = 0; nj < 2; ++nj)
      acc[mi][nj] = (f32x4){0.f, 0.f, 0.f, 0.f};

  const int wm = w & 3, wn = w >> 2;      // wave tile: rows 64*wm, cols 32*wn
  const int lr = l & 15, lg = l >> 4;
  const int arow_l = (w << 3) + (l >> 3); // A stage row (per rep +64)
  const int acl = l & 7;                  // linear chunk within row
  const int bn_l = t >> 3;                // B stage: W row (output col)
  const int bcc = t & 7;                  // B stage: chunk

  for (int tt = 0; tt < 4; ++tt) {
    const int kk = k0 + (tt << 6);
    __syncthreads();                      // LDS safe to overwrite
    // stage A: 256x64 bf16, linear LDS dest, source chunk pre-swizzled
#pragma unroll
    for (int r = 0; r < 4; ++r) {
      const int row = (r << 6) + arow_l;
      const int cs = acl ^ (row & 7);
      async_cp16(A + ((size_t)row << 12) + kk + (cs << 3),
                 &As[(r << 12) + (w << 9)]);
    }
    // stage B: 64(out col) x 64(k) fp32 -> bf16, swizzled ds_write
    {
      const float* wsrc = W + ((size_t)(colg0 + bn_l) << 12) + kk + (bcc << 3);
      const float4 f0 = *reinterpret_cast<const float4*>(wsrc);
      const float4 f1 = *reinterpret_cast<const float4*>(wsrc + 4);
      uint4 pk;
      pk.x = pack2bf(f0.x, f0.y);
      pk.y = pack2bf(f0.z, f0.w);
      pk.z = pack2bf(f1.x, f1.y);
      pk.w = pack2bf(f1.z, f1.w);
      *reinterpret_cast<uint4*>(&Bs[(bn_l << 6) + ((bcc ^ (bn_l & 7)) << 3)]) = pk;
    }
    __syncthreads();                      // vmcnt(0)+lgkmcnt(0)+barrier
#pragma unroll
    for (int ks = 0; ks < 2; ++ks) {
      const int cg = (ks << 2) + lg;
      bf16x8 av[4], bv[2];
#pragma unroll
      for (int mi = 0; mi < 4; ++mi) {
        const int fr = (wm << 6) + (mi << 4) + lr;
        av[mi] = *reinterpret_cast<const bf16x8*>(&As[(fr << 6) + ((cg ^ (fr & 7)) << 3)]);
      }
#pragma unroll
      for (int nj = 0; nj < 2; ++nj) {
        const int fc = (wn << 5) + (nj << 4) + lr;
        bv[nj] = *reinterpret_cast<const bf16x8*>(&Bs[(fc << 6) + ((cg ^ (fc & 7)) << 3)]);
      }
#pragma unroll
      for (int mi = 0; mi < 4; ++mi)
#pragma unroll
        for (int nj = 0; nj < 2; ++nj)
          acc[mi][nj] = __builtin_amdgcn_mfma_f32_16x16x32_bf16(
              av[mi], bv[nj], acc[mi][nj], 0, 0, 0);
    }
  }

  u16* pout = part + (size_t)kz * PSTRIDE;
#pragma unroll
  for (int mi = 0; mi < 4; ++mi)
#pragma unroll
    for (int nj = 0; nj < 2; ++nj) {
      const int col = colg0 + (wn << 5) + (nj << 4) + lr;
#pragma unroll
      for (int j = 0; j < 4; ++j) {
        const int row = (wm << 6) + (mi << 4) + (lg << 2) + j;
        pout[((size_t)row << 12) + col] = f2bf(acc[mi][nj][j]);
      }
    }
}

// ---------------------------------------------------------------------------
// Per-sample fused update, 512 threads. Cayley collapsed analytically:
//   new_A = A - H^2 * F @ (A^T F) @ (A^T A)   (exact to fp32; H^4 ~ 1e-13)
// ---------------------------------------------------------------------------
struct UpdSmem {                     // 35.1 KB (dY overlaid with stiefel temps)
  float U[64][17], V[64][17], P[64][17], Q[64][17];
  float S[16][16];
  float sinv[16];
  union {
    float dY[64][68];                // live: partial-sum .. P/Q formation
    struct {                         // live: after P/Q formed
      float F[64][17];
      float T1[16][17], G1[16][17], G2[16][17], M1[16][17], dSs[16][17];
      float RS[512];
    };
  };
};

__device__ __forceinline__ void stiefel_update512(
    UpdSmem& m, float (&Am)[64][17], float (&Dm)[64][17],
    int t, float* __restrict__ gout, size_t ub)
{
  const int p = t >> 3;
  const int j0 = (t << 1) & 15;
  {
    const int half = t & 1, i = t >> 5, j = (t >> 1) & 15;
    float a = 0.f;
    const int r0 = half << 5;
    for (int r = r0; r < r0 + 32; ++r) a += Am[r][i] * Dm[r][j];
    m.RS[t] = a;
  }
  __syncthreads();
  if (t < 256) m.T1[t >> 4][t & 15] = m.RS[t << 1] + m.RS[(t << 1) + 1];
  __syncthreads();
  {
    float f0 = Dm[p][j0], f1 = Dm[p][j0 + 1];
    for (int k = 0; k < 16; ++k) {
      const float ak = Am[p][k];
      f0 -= ak * m.T1[k][j0];
      f1 -= ak * m.T1[k][j0 + 1];
    }
    m.F[p][j0] = f0; m.F[p][j0 + 1] = f1;
  }
  __syncthreads();
  if (t < 256) {
    const int i = t >> 4, j = t & 15;
    float g = 0.f;
    for (int r = 0; r < 64; ++r) g += Am[r][i] * m.F[r][j];
    m.G1[i][j] = g;
  } else {
    const int tt = t - 256, i = tt >> 4, j = tt & 15;
    float g = 0.f;
    for (int r = 0; r < 64; ++r) g += Am[r][i] * Am[r][j];
    m.G2[i][j] = g;
  }
  __syncthreads();
  if (t < 256) {
    const int i = t >> 4, j = t & 15;
    float mm = 0.f;
    for (int k = 0; k < 16; ++k) mm += m.G1[i][k] * m.G2[k][j];
    m.M1[i][j] = mm;
  }
  __syncthreads();
  {
    float a0 = 0.f, a1 = 0.f;
    for (int k = 0; k < 16; ++k) {
      const float fk = m.F[p][k];
      a0 += fk * m.M1[k][j0];
      a1 += fk * m.M1[k][j0 + 1];
    }
    const float n0 = Am[p][j0] - 1e-6f * a0;
    const float n1 = Am[p][j0 + 1] - 1e-6f * a1;
    __syncthreads();
    Am[p][j0] = n0; Am[p][j0 + 1] = n1;
    *reinterpret_cast<float2*>(gout + ub + (p << 4) + j0) = make_float2(n0, n1);
  }
  __syncthreads();
}

__device__ __forceinline__ void write_xf_tail(
    UpdSmem& m, int t, int b, float* __restrict__ Xf, u16* __restrict__ Xfb,
    float* __restrict__ outL_plane)
{
  const int p = t >> 3;
  const int j0 = (t << 1) & 15;
  {
    float a0 = 0.f, a1 = 0.f;
    for (int k = 0; k < 16; ++k) {
      const float uk = m.U[p][k];
      a0 += uk * m.S[k][j0];
      a1 += uk * m.S[k][j0 + 1];
    }
    m.P[p][j0] = a0; m.P[p][j0 + 1] = a1;
  }
  __syncthreads();
  {
    const int q0 = (t & 7) << 3;
    float res[8];
#pragma unroll
    for (int e = 0; e < 8; ++e) res[e] = 0.f;
    for (int i = 0; i < 16; ++i) {
      const float pi = m.P[p][i];
#pragma unroll
      for (int e = 0; e < 8; ++e) res[e] += pi * m.V[q0 + e][i];
    }
    const size_t ko = ((size_t)b << 12) + (p << 6) + q0;
    float4* xo = reinterpret_cast<float4*>(Xf + ko);
    const float4 r0 = make_float4(res[0], res[1], res[2], res[3]);
    const float4 r1 = make_float4(res[4], res[5], res[6], res[7]);
    xo[0] = r0; xo[1] = r1;
    uint4 pk;
    pk.x = pack2bf(res[0], res[1]); pk.y = pack2bf(res[2], res[3]);
    pk.z = pack2bf(res[4], res[5]); pk.w = pack2bf(res[6], res[7]);
    *reinterpret_cast<uint4*>(Xfb + ko) = pk;
    if (outL_plane != nullptr) {
      float4* op = reinterpret_cast<float4*>(outL_plane + ko);
      op[0] = r0; op[1] = r1;
    }
  }
}

__global__ __launch_bounds__(512) void update_kernel(
    const u16* __restrict__ part, const float* __restrict__ bias,
    float* __restrict__ u_g, float* __restrict__ v_g, float* __restrict__ s_g,
    float* __restrict__ Xf, u16* __restrict__ Xfb,
    float* __restrict__ outL, int layer)
{
  const int b = blockIdx.x, t = threadIdx.x;
  __shared__ __align__(16) UpdSmem m;
  float* outL_plane = outL + (size_t)layer * PLANE;

  const size_t ub = (size_t)b << 10;
  {
    const float2 u2 = *reinterpret_cast<const float2*>(u_g + ub + (t << 1));
    const float2 v2 = *reinterpret_cast<const float2*>(v_g + ub + (t << 1));
    const int r = t >> 3, c = (t & 7) << 1;
    m.U[r][c] = u2.x; m.U[r][c + 1] = u2.y;
    m.V[r][c] = v2.x; m.V[r][c + 1] = v2.y;
    if (t < 256) m.S[t >> 4][t & 15] = s_g[((size_t)b << 8) + t];
  }
  __syncthreads();
  if (t < 16) m.sinv[t] = 1.0f / m.S[t][t];
  // dY = relu(sum of 16 bf16 partials + bias); 8 elems per thread
  {
    const u16* p0 = part + ((size_t)b << 12) + (t << 3);
    float x[8];
#pragma unroll
    for (int e = 0; e < 8; ++e) x[e] = 0.f;
#pragma unroll
    for (int kzi = 0; kzi < SPLIT_K; ++kzi) {
      const uint4 v = *reinterpret_cast<const uint4*>(p0 + (size_t)kzi * PSTRIDE);
      x[0] += bf2f((u16)(v.x & 0xffff)); x[1] += bf2f((u16)(v.x >> 16));
      x[2] += bf2f((u16)(v.y & 0xffff)); x[3] += bf2f((u16)(v.y >> 16));
      x[4] += bf2f((u16)(v.z & 0xffff)); x[5] += bf2f((u16)(v.z >> 16));
      x[6] += bf2f((u16)(v.w & 0xffff)); x[7] += bf2f((u16)(v.w >> 16));
    }
    if (bias != nullptr) {
      const float4 b0 = *reinterpret_cast<const float4*>(bias + (t << 3));
      const float4 b1 = *reinterpret_cast<const float4*>(bias + (t << 3) + 4);
      x[0] += b0.x; x[1] += b0.y; x[2] += b0.z; x[3] += b0.w;
      x[4] += b1.x; x[5] += b1.y; x[6] += b1.z; x[7] += b1.w;
    }
    const int r = t >> 3, c = (t & 7) << 3;
    float4* d0 = reinterpret_cast<float4*>(&m.dY[r][c]);
    d0[0] = make_float4(fmaxf(x[0], 0.f), fmaxf(x[1], 0.f), fmaxf(x[2], 0.f), fmaxf(x[3], 0.f));
    d0[1] = make_float4(fmaxf(x[4], 0.f), fmaxf(x[5], 0.f), fmaxf(x[6], 0.f), fmaxf(x[7], 0.f));
  }
  __syncthreads();
  const int p = t >> 3;
  const int j0 = (t << 1) & 15;
  {
    float a0 = 0.f, a1 = 0.f;
    for (int q = 0; q < 64; ++q) {
      const float d = m.dY[p][q];
      a0 += d * m.V[q][j0];
      a1 += d * m.V[q][j0 + 1];
    }
    float b0 = 0.f, b1 = 0.f;
    for (int r = 0; r < 64; ++r) {
      const float d = m.dY[r][p];
      b0 += d * m.U[r][j0];
      b1 += d * m.U[r][j0 + 1];
    }
    m.P[p][j0] = a0; m.P[p][j0 + 1] = a1;
    m.Q[p][j0] = b0; m.Q[p][j0 + 1] = b1;
  }
  __syncthreads();           // dY dead from here; union side F/T1/../RS live
  {
    const int half = t & 1, i = t >> 5, j = (t >> 1) & 15;
    float a = 0.f;
    const int r0 = half << 5;
    for (int r = r0; r < r0 + 32; ++r) a += m.U[r][i] * m.P[r][j];
    m.RS[t] = a;
  }
  __syncthreads();
  if (t < 256) m.dSs[t >> 4][t & 15] = m.RS[t << 1] + m.RS[(t << 1) + 1];
  __syncthreads();
  for (int i = t; i < 1024; i += 512) {
    const int r = i >> 4, c = i & 15;
    const float sc = m.sinv[c];
    m.P[r][c] *= sc;
    m.Q[r][c] *= sc;
  }
  __syncthreads();

  stiefel_update512(m, m.U, m.P, t, u_g, ub);
  stiefel_update512(m, m.V, m.Q, t, v_g, ub);

  if (t < 256) {
    const int i = t >> 4, j = t & 15;
    const float ns = m.S[i][j] + 1e-3f * m.dSs[i][j];
    m.S[i][j] = ns;
    s_g[((size_t)b << 8) + t] = ns;
  }
  __syncthreads();
  write_xf_tail(m, t, b, Xf, Xfb, outL_plane);
}

// ---------------------------------------------------------------------------
// Init: unpack u, s, v from X (per-sample stride 3*1024); Xf0 = u s v^T.
// ---------------------------------------------------------------------------
__global__ __launch_bounds__(512) void init_kernel(
    const float* __restrict__ X, float* __restrict__ u_g, float* __restrict__ v_g,
    float* __restrict__ s_g, float* __restrict__ Xf, u16* __restrict__ Xfb)
{
  const int b = blockIdx.x, t = threadIdx.x;
  __shared__ __align__(16) UpdSmem m;
  const float* xb = X + (size_t)b * 3072;
  const size_t ub = (size_t)b << 10;
  {
    const float2 u2 = *reinterpret_cast<const float2*>(xb + (t << 1));
    const int r = t >> 3, c = (t & 7) << 1;
    m.U[r][c] = u2.x; m.U[r][c + 1] = u2.y;
    *reinterpret_cast<float2*>(u_g + ub + (t << 1)) = u2;
    if (t < 256) {
      const float sv = xb[1024 + t];
      m.S[t >> 4][t & 15] = sv;
      s_g[((size_t)b << 8) + t] = sv;
    }
    const float2 v2 = *reinterpret_cast<const float2*>(xb + 2048 + (t << 1));
    const int g2 = t << 1;
    const int iv = g2 >> 6, q = g2 & 63;
    m.V[q][iv] = v2.x; m.V[q + 1][iv] = v2.y;
    v_g[ub + (size_t)q * 16 + iv] = v2.x;
    v_g[ub + (size_t)(q + 1) * 16 + iv] = v2.y;
  }
  __syncthreads();
  write_xf_tail(m, t, b, Xf, Xfb, nullptr);
}

// ---------------------------------------------------------------------------
// Pack: outT[b,k,9] <- outL[9][b,k] via LDS, coalesced both sides.
// ---------------------------------------------------------------------------
__global__ __launch_bounds__(256) void pack_kernel(
    const float* __restrict__ outL, float* __restrict__ outT)
{
  const int t = threadIdx.x;
  const int base = blockIdx.x << 8;
  __shared__ float buf[256 * 9];
#pragma unroll
  for (int l = 0; l < 9; ++l)
    buf[t * 9 + l] = outL[(size_t)l * PLANE + base + t];
  __syncthreads();
  const float4* b4 = reinterpret_cast<const float4*>(buf);
  float4* o4 = reinterpret_cast<float4*>(outT + (size_t)base * 9);
  for (int i = t; i < 576; i += 256) o4[i] = b4[i];
}

// ---------------------------------------------------------------------------
// Classifier: logits = Xf @ Wc^T + bc ; softmax.
// ---------------------------------------------------------------------------
__global__ __launch_bounds__(256) void classifier_kernel(
    const float* __restrict__ Xf, const float* __restrict__ Wc,
    const float* __restrict__ bc, float* __restrict__ pred, float* __restrict__ cls)
{
  const int b = blockIdx.x, t = threadIdx.x;
  const int lane = t & 63, w = t >> 6;
  __shared__ float red[4][10];
  float acc[10];
#pragma unroll
  for (int c = 0; c < 10; ++c) acc[c] = 0.f;
  const float* xr = Xf + ((size_t)b << 12);
  for (int k = t; k < 4096; k += 256) {
    const float x = xr[k];
#pragma unroll
    for (int c = 0; c < 10; ++c) acc[c] += x * Wc[c * 4096 + k];
  }
#pragma unroll
  for (int c = 0; c < 10; ++c)
    for (int off = 32; off; off >>= 1) acc[c] += __shfl_xor(acc[c], off);
  if (lane == 0)
#pragma unroll
    for (int c = 0; c < 10; ++c) red[w][c] = acc[c];
  __syncthreads();
  if (t == 0) {
    float lg[10], ex[10];
    float m = -1e30f;
#pragma unroll
    for (int c = 0; c < 10; ++c) {
      lg[c] = red[0][c] + red[1][c] + red[2][c] + red[3][c] + bc[c];
      m = fmaxf(m, lg[c]);
    }
    float s = 0.f;
#pragma unroll
    for (int c = 0; c < 10; ++c) { ex[c] = expf(lg[c] - m); s += ex[c]; }
    const float inv = 1.f / s;
#pragma unroll
    for (int c = 0; c < 10; ++c) {
      cls[b * 10 + c] = lg[c];
      pred[b * 10 + c] = ex[c] * inv;
    }
  }
}

extern "C" void kernel_launch(void* const* d_in, const int* in_sizes, int n_in,
                              void* d_out, int out_size, void* d_ws, size_t ws_size,
                              hipStream_t stream) {
  (void)in_sizes; (void)n_in; (void)out_size; (void)ws_size;
  const float* X  = (const float*)d_in[0];
  const float* W0 = (const float*)d_in[1];
  const float* W  = (const float*)d_in[2];
  const float* bb = (const float*)d_in[3];
  const float* Wc = (const float*)d_in[4];
  const float* bc = (const float*)d_in[5];

  float* out_pred  = (float*)d_out;
  float* out_cls   = out_pred + 2560;
  float* out_trans = out_pred + 5120;

  char* ws = (char*)d_ws;
  float* Xf   = (float*)(ws);                      // 4 MB
  u16*   part = (u16*)  (ws + (4ull << 20));       // 32 MB (16 bf16 split-K planes)
  float* u_g  = (float*)(ws + (36ull << 20));      // 1 MB
  float* v_g  = (float*)(ws + (37ull << 20));      // 1 MB
  float* s_g  = (float*)(ws + (38ull << 20));      // 256 KB
  u16*   Xfb  = (u16*)  (ws + (39ull << 20));      // 2 MB
  float* outL = (float*)(ws + (41ull << 20));      // 36 MB (9 layer planes)

  init_kernel<<<NB, 512, 0, stream>>>(X, u_g, v_g, s_g, Xf, Xfb);
  for (int i = 0; i <= 8; ++i) {
    const float* Wl = (i == 0) ? W0 : W + (size_t)(i - 1) * DD * DD;
    gemm_kernel<<<dim3(64, SPLIT_K), 512, 0, stream>>>(Xfb, Wl, part);
    update_kernel<<<NB, 512, 0, stream>>>(
        part, (i == 0) ? nullptr : (bb + (size_t)(i - 1) * DD),
        u_g, v_g, s_g, Xf, Xfb, outL, i);
  }
  pack_kernel<<<4096, 256, 0, stream>>>(outL, out_trans);
  classifier_kernel<<<NB, 256, 0, stream>>>(Xf, Wc, bc, out_pred, out_cls);
}

// Round 11
// 439.214 us; speedup vs baseline: 1.4933x; 1.4933x over previous
//
#include <hip/hip_runtime.h>
#include <math.h>

typedef unsigned short u16;
typedef unsigned int u32;
using bf16x8 = __attribute__((ext_vector_type(8))) short;
using f32x4  = __attribute__((ext_vector_type(4))) float;

#define DD 4096
#define NB 256            // batch
#define SPLIT_K 4
#define PSTRIDE (NB * DD) // elements per partial plane
#define PLANE (NB * DD)   // floats per transform layer plane

__device__ __forceinline__ u16 f2bf(float f) {
  unsigned int u = __float_as_uint(f);
  u += 0x7fffu + ((u >> 16) & 1u);   // RNE
  return (u16)(u >> 16);
}
__device__ __forceinline__ float bf2f(u16 h) {
  return __uint_as_float((u32)h << 16);
}
__device__ __forceinline__ unsigned int pack2bf(float a, float b) {
  return (unsigned int)f2bf(a) | ((unsigned int)f2bf(b) << 16);
}
__device__ __forceinline__ void async_cp16(const u16* g, u16* l) {
  __builtin_amdgcn_global_load_lds(
      (const __attribute__((address_space(1))) unsigned int*)g,
      (__attribute__((address_space(3))) unsigned int*)l, 16, 0, 0);
}

// ---------------------------------------------------------------------------
// GEMM v2: part[kz] = Xf(bf16) @ W^T, output bf16.
// Tile 128x64 (M-split 2), K-chunk 1024 (16 iters of BK=64).
// grid (64 nt, 8 = mt*4+...) -> 512 WGs; 24 KB LDS -> 4 WG/CU; VGPR<=64 via
// launch_bounds(512,8) -> 32 waves/CU. TLP + long K-chunks amortize the
// per-iter drain; partial traffic halves (4 bf16 planes).
// ---------------------------------------------------------------------------
__global__ __launch_bounds__(512, 8) void gemm_kernel(
    const u16* __restrict__ A, const float* __restrict__ W,
    u16* __restrict__ part)
{
  const int nt = blockIdx.x;
  const int mt = blockIdx.y & 1;
  const int kz = blockIdx.y >> 1;
  const int t = threadIdx.x;
  const int w = t >> 6, l = t & 63;

  __shared__ __align__(16) u16 As[128 * 64];   // 16 KB
  __shared__ __align__(16) u16 Bs[64 * 64];    // 8 KB

  const int colg0 = nt << 6;
  const int m0 = mt << 7;
  const int k0 = kz << 10;                     // K-chunk of 1024

  f32x4 acc[2][2];
#pragma unroll
  for (int mi = 0; mi < 2; ++mi)
#pragma unroll
    for (int nj = 0; nj < 2; ++nj)
      acc[mi][nj] = (f32x4){0.f, 0.f, 0.f, 0.f};

  const int wm = w & 3, wn = w >> 2;      // wave tile: rows 32*wm, cols 32*wn
  const int lr = l & 15, lg = l >> 4;
  const int arow_l = (w << 3) + (l >> 3); // A stage row (+64 for 2nd load)
  const int acl = l & 7;                  // linear chunk within row
  const int bn_l = t >> 3;                // B stage: W row (output col)
  const int bcc = t & 7;                  // B stage: chunk

  for (int tt = 0; tt < 16; ++tt) {
    const int kk = k0 + (tt << 6);
    __syncthreads();                      // LDS safe to overwrite
    // stage A: 128x64 bf16, linear LDS dest, source chunk pre-swizzled
#pragma unroll
    for (int r2 = 0; r2 < 2; ++r2) {
      const int row = (r2 << 6) + arow_l;
      const int cs = acl ^ (row & 7);
      async_cp16(A + ((size_t)(m0 + row) << 12) + kk + (cs << 3),
                 &As[(r2 << 12) + (w << 9)]);
    }
    // stage B: 64(out col) x 64(k) fp32 -> bf16, swizzled ds_write
    {
      const float* wsrc = W + ((size_t)(colg0 + bn_l) << 12) + kk + (bcc << 3);
      const float4 f0 = *reinterpret_cast<const float4*>(wsrc);
      const float4 f1 = *reinterpret_cast<const float4*>(wsrc + 4);
      uint4 pk;
      pk.x = pack2bf(f0.x, f0.y);
      pk.y = pack2bf(f0.z, f0.w);
      pk.z = pack2bf(f1.x, f1.y);
      pk.w = pack2bf(f1.z, f1.w);
      *reinterpret_cast<uint4*>(&Bs[(bn_l << 6) + ((bcc ^ (bn_l & 7)) << 3)]) = pk;
    }
    __syncthreads();                      // vmcnt(0)+lgkmcnt(0)+barrier
#pragma unroll
    for (int ks = 0; ks < 2; ++ks) {
      const int cg = (ks << 2) + lg;
      bf16x8 av[2], bv[2];
#pragma unroll
      for (int mi = 0; mi < 2; ++mi) {
        const int fr = (wm << 5) + (mi << 4) + lr;
        av[mi] = *reinterpret_cast<const bf16x8*>(&As[(fr << 6) + ((cg ^ (fr & 7)) << 3)]);
      }
#pragma unroll
      for (int nj = 0; nj < 2; ++nj) {
        const int fc = (wn << 5) + (nj << 4) + lr;
        bv[nj] = *reinterpret_cast<const bf16x8*>(&Bs[(fc << 6) + ((cg ^ (fc & 7)) << 3)]);
      }
#pragma unroll
      for (int mi = 0; mi < 2; ++mi)
#pragma unroll
        for (int nj = 0; nj < 2; ++nj)
          acc[mi][nj] = __builtin_amdgcn_mfma_f32_16x16x32_bf16(
              av[mi], bv[nj], acc[mi][nj], 0, 0, 0);
    }
  }

  u16* pout = part + (size_t)kz * PSTRIDE;
#pragma unroll
  for (int mi = 0; mi < 2; ++mi)
#pragma unroll
    for (int nj = 0; nj < 2; ++nj) {
      const int col = colg0 + (wn << 5) + (nj << 4) + lr;
#pragma unroll
      for (int j = 0; j < 4; ++j) {
        const int row = m0 + (wm << 5) + (mi << 4) + (lg << 2) + j;
        pout[((size_t)row << 12) + col] = f2bf(acc[mi][nj][j]);
      }
    }
}

// ---------------------------------------------------------------------------
// Per-sample fused update, 512 threads. Cayley collapsed analytically:
//   new_A = A - H^2 * F @ (A^T F) @ (A^T A)   (exact to fp32; H^4 ~ 1e-13)
// dY kept in BOTH orientations (dYT stride 69) so P and Q loops both read
// rows conflict-free (kills the measured 12.7M-cycle 8-way conflicts).
// ---------------------------------------------------------------------------
struct UpdSmem {
  float U[64][17], V[64][17], P[64][17], Q[64][17];
  float S[16][16];
  float sinv[16];
  union {
    struct {                         // live: partial-sum .. P/Q formation
      float dY[64][68];
      float dYT[64][69];
    };
    struct {                         // live: after P/Q formed
      float F[64][17];
      float T1[16][17], G1[16][17], G2[16][17], M1[16][17], dSs[16][17];
      float RS[512];
    };
  };
};

__device__ __forceinline__ void stiefel_update512(
    UpdSmem& m, float (&Am)[64][17], float (&Dm)[64][17],
    int t, float* __restrict__ gout, size_t ub)
{
  const int p = t >> 3;
  const int j0 = (t << 1) & 15;
  {
    const int half = t & 1, i = t >> 5, j = (t >> 1) & 15;
    float a = 0.f;
    const int r0 = half << 5;
    for (int r = r0; r < r0 + 32; ++r) a += Am[r][i] * Dm[r][j];
    m.RS[t] = a;
  }
  __syncthreads();
  if (t < 256) m.T1[t >> 4][t & 15] = m.RS[t << 1] + m.RS[(t << 1) + 1];
  __syncthreads();
  {
    float f0 = Dm[p][j0], f1 = Dm[p][j0 + 1];
    for (int k = 0; k < 16; ++k) {
      const float ak = Am[p][k];
      f0 -= ak * m.T1[k][j0];
      f1 -= ak * m.T1[k][j0 + 1];
    }
    m.F[p][j0] = f0; m.F[p][j0 + 1] = f1;
  }
  __syncthreads();
  if (t < 256) {
    const int i = t >> 4, j = t & 15;
    float g = 0.f;
    for (int r = 0; r < 64; ++r) g += Am[r][i] * m.F[r][j];
    m.G1[i][j] = g;
  } else {
    const int tt = t - 256, i = tt >> 4, j = tt & 15;
    float g = 0.f;
    for (int r = 0; r < 64; ++r) g += Am[r][i] * Am[r][j];
    m.G2[i][j] = g;
  }
  __syncthreads();
  if (t < 256) {
    const int i = t >> 4, j = t & 15;
    float mm = 0.f;
    for (int k = 0; k < 16; ++k) mm += m.G1[i][k] * m.G2[k][j];
    m.M1[i][j] = mm;
  }
  __syncthreads();
  {
    float a0 = 0.f, a1 = 0.f;
    for (int k = 0; k < 16; ++k) {
      const float fk = m.F[p][k];
      a0 += fk * m.M1[k][j0];
      a1 += fk * m.M1[k][j0 + 1];
    }
    const float n0 = Am[p][j0] - 1e-6f * a0;
    const float n1 = Am[p][j0 + 1] - 1e-6f * a1;
    __syncthreads();
    Am[p][j0] = n0; Am[p][j0 + 1] = n1;
    *reinterpret_cast<float2*>(gout + ub + (p << 4) + j0) = make_float2(n0, n1);
  }
  __syncthreads();
}

__device__ __forceinline__ void write_xf_tail(
    UpdSmem& m, int t, int b, float* __restrict__ Xf, u16* __restrict__ Xfb,
    float* __restrict__ outL_plane)
{
  const int p = t >> 3;
  const int j0 = (t << 1) & 15;
  {
    float a0 = 0.f, a1 = 0.f;
    for (int k = 0; k < 16; ++k) {
      const float uk = m.U[p][k];
      a0 += uk * m.S[k][j0];
      a1 += uk * m.S[k][j0 + 1];
    }
    m.P[p][j0] = a0; m.P[p][j0 + 1] = a1;
  }
  __syncthreads();
  {
    const int q0 = (t & 7) << 3;
    float res[8];
#pragma unroll
    for (int e = 0; e < 8; ++e) res[e] = 0.f;
    for (int i = 0; i < 16; ++i) {
      const float pi = m.P[p][i];
#pragma unroll
      for (int e = 0; e < 8; ++e) res[e] += pi * m.V[q0 + e][i];
    }
    const size_t ko = ((size_t)b << 12) + (p << 6) + q0;
    float4* xo = reinterpret_cast<float4*>(Xf + ko);
    const float4 r0 = make_float4(res[0], res[1], res[2], res[3]);
    const float4 r1 = make_float4(res[4], res[5], res[6], res[7]);
    xo[0] = r0; xo[1] = r1;
    uint4 pk;
    pk.x = pack2bf(res[0], res[1]); pk.y = pack2bf(res[2], res[3]);
    pk.z = pack2bf(res[4], res[5]); pk.w = pack2bf(res[6], res[7]);
    *reinterpret_cast<uint4*>(Xfb + ko) = pk;
    if (outL_plane != nullptr) {
      float4* op = reinterpret_cast<float4*>(outL_plane + ko);
      op[0] = r0; op[1] = r1;
    }
  }
}

__global__ __launch_bounds__(512) void update_kernel(
    const u16* __restrict__ part, const float* __restrict__ bias,
    float* __restrict__ u_g, float* __restrict__ v_g, float* __restrict__ s_g,
    float* __restrict__ Xf, u16* __restrict__ Xfb,
    float* __restrict__ outL, int layer)
{
  const int b = blockIdx.x, t = threadIdx.x;
  __shared__ __align__(16) UpdSmem m;
  float* outL_plane = outL + (size_t)layer * PLANE;

  const size_t ub = (size_t)b << 10;
  {
    const float2 u2 = *reinterpret_cast<const float2*>(u_g + ub + (t << 1));
    const float2 v2 = *reinterpret_cast<const float2*>(v_g + ub + (t << 1));
    const int r = t >> 3, c = (t & 7) << 1;
    m.U[r][c] = u2.x; m.U[r][c + 1] = u2.y;
    m.V[r][c] = v2.x; m.V[r][c + 1] = v2.y;
    if (t < 256) m.S[t >> 4][t & 15] = s_g[((size_t)b << 8) + t];
  }
  __syncthreads();
  if (t < 16) m.sinv[t] = 1.0f / m.S[t][t];
  // dY = relu(sum of 4 bf16 partials + bias); 8 elems per thread; dual-store
  {
    const u16* p0 = part + ((size_t)b << 12) + (t << 3);
    float x[8];
#pragma unroll
    for (int e = 0; e < 8; ++e) x[e] = 0.f;
#pragma unroll
    for (int kzi = 0; kzi < SPLIT_K; ++kzi) {
      const uint4 v = *reinterpret_cast<const uint4*>(p0 + (size_t)kzi * PSTRIDE);
      x[0] += bf2f((u16)(v.x & 0xffff)); x[1] += bf2f((u16)(v.x >> 16));
      x[2] += bf2f((u16)(v.y & 0xffff)); x[3] += bf2f((u16)(v.y >> 16));
      x[4] += bf2f((u16)(v.z & 0xffff)); x[5] += bf2f((u16)(v.z >> 16));
      x[6] += bf2f((u16)(v.w & 0xffff)); x[7] += bf2f((u16)(v.w >> 16));
    }
    if (bias != nullptr) {
      const float4 b0 = *reinterpret_cast<const float4*>(bias + (t << 3));
      const float4 b1 = *reinterpret_cast<const float4*>(bias + (t << 3) + 4);
      x[0] += b0.x; x[1] += b0.y; x[2] += b0.z; x[3] += b0.w;
      x[4] += b1.x; x[5] += b1.y; x[6] += b1.z; x[7] += b1.w;
    }
    const int r = t >> 3, c = (t & 7) << 3;
#pragma unroll
    for (int e = 0; e < 8; ++e) x[e] = fmaxf(x[e], 0.f);
    float4* d0 = reinterpret_cast<float4*>(&m.dY[r][c]);
    d0[0] = make_float4(x[0], x[1], x[2], x[3]);
    d0[1] = make_float4(x[4], x[5], x[6], x[7]);
#pragma unroll
    for (int e = 0; e < 8; ++e) m.dYT[c + e][r] = x[e];
  }
  __syncthreads();
  const int p = t >> 3;
  const int j0 = (t << 1) & 15;
  // P = dY @ V ; Q = dY^T @ U  (both row-major reads, conflict-free)
  {
    float a0 = 0.f, a1 = 0.f;
    for (int q = 0; q < 64; ++q) {
      const float d = m.dY[p][q];
      a0 += d * m.V[q][j0];
      a1 += d * m.V[q][j0 + 1];
    }
    float b0 = 0.f, b1 = 0.f;
    for (int r = 0; r < 64; ++r) {
      const float d = m.dYT[p][r];
      b0 += d * m.U[r][j0];
      b1 += d * m.U[r][j0 + 1];
    }
    m.P[p][j0] = a0; m.P[p][j0 + 1] = a1;
    m.Q[p][j0] = b0; m.Q[p][j0 + 1] = b1;
  }
  __syncthreads();           // dY/dYT dead from here; union stiefel side live
  {
    const int half = t & 1, i = t >> 5, j = (t >> 1) & 15;
    float a = 0.f;
    const int r0 = half << 5;
    for (int r = r0; r < r0 + 32; ++r) a += m.U[r][i] * m.P[r][j];
    m.RS[t] = a;
  }
  __syncthreads();
  if (t < 256) m.dSs[t >> 4][t & 15] = m.RS[t << 1] + m.RS[(t << 1) + 1];
  __syncthreads();
  for (int i = t; i < 1024; i += 512) {
    const int r = i >> 4, c = i & 15;
    const float sc = m.sinv[c];
    m.P[r][c] *= sc;
    m.Q[r][c] *= sc;
  }
  __syncthreads();

  stiefel_update512(m, m.U, m.P, t, u_g, ub);
  stiefel_update512(m, m.V, m.Q, t, v_g, ub);

  if (t < 256) {
    const int i = t >> 4, j = t & 15;
    const float ns = m.S[i][j] + 1e-3f * m.dSs[i][j];
    m.S[i][j] = ns;
    s_g[((size_t)b << 8) + t] = ns;
  }
  __syncthreads();
  write_xf_tail(m, t, b, Xf, Xfb, outL_plane);
}

// ---------------------------------------------------------------------------
// Init: unpack u, s, v from X (per-sample stride 3*1024); Xf0 = u s v^T.
// ---------------------------------------------------------------------------
__global__ __launch_bounds__(512) void init_kernel(
    const float* __restrict__ X, float* __restrict__ u_g, float* __restrict__ v_g,
    float* __restrict__ s_g, float* __restrict__ Xf, u16* __restrict__ Xfb)
{
  const int b = blockIdx.x, t = threadIdx.x;
  __shared__ __align__(16) UpdSmem m;
  const float* xb = X + (size_t)b * 3072;
  const size_t ub = (size_t)b << 10;
  {
    const float2 u2 = *reinterpret_cast<const float2*>(xb + (t << 1));
    const int r = t >> 3, c = (t & 7) << 1;
    m.U[r][c] = u2.x; m.U[r][c + 1] = u2.y;
    *reinterpret_cast<float2*>(u_g + ub + (t << 1)) = u2;
    if (t < 256) {
      const float sv = xb[1024 + t];
      m.S[t >> 4][t & 15] = sv;
      s_g[((size_t)b << 8) + t] = sv;
    }
    const float2 v2 = *reinterpret_cast<const float2*>(xb + 2048 + (t << 1));
    const int g2 = t << 1;
    const int iv = g2 >> 6, q = g2 & 63;
    m.V[q][iv] = v2.x; m.V[q + 1][iv] = v2.y;
    v_g[ub + (size_t)q * 16 + iv] = v2.x;
    v_g[ub + (size_t)(q + 1) * 16 + iv] = v2.y;
  }
  __syncthreads();
  write_xf_tail(m, t, b, Xf, Xfb, nullptr);
}

// ---------------------------------------------------------------------------
// Pack: outT[b,k,9] <- outL[9][b,k] via LDS, coalesced both sides.
// ---------------------------------------------------------------------------
__global__ __launch_bounds__(256) void pack_kernel(
    const float* __restrict__ outL, float* __restrict__ outT)
{
  const int t = threadIdx.x;
  const int base = blockIdx.x << 8;
  __shared__ float buf[256 * 9];
#pragma unroll
  for (int l = 0; l < 9; ++l)
    buf[t * 9 + l] = outL[(size_t)l * PLANE + base + t];
  __syncthreads();
  const float4* b4 = reinterpret_cast<const float4*>(buf);
  float4* o4 = reinterpret_cast<float4*>(outT + (size_t)base * 9);
  for (int i = t; i < 576; i += 256) o4[i] = b4[i];
}

// ---------------------------------------------------------------------------
// Classifier: logits = Xf @ Wc^T + bc ; softmax.
// ---------------------------------------------------------------------------
__global__ __launch_bounds__(256) void classifier_kernel(
    const float* __restrict__ Xf, const float* __restrict__ Wc,
    const float* __restrict__ bc, float* __restrict__ pred, float* __restrict__ cls)
{
  const int b = blockIdx.x, t = threadIdx.x;
  const int lane = t & 63, w = t >> 6;
  __shared__ float red[4][10];
  float acc[10];
#pragma unroll
  for (int c = 0; c < 10; ++c) acc[c] = 0.f;
  const float* xr = Xf + ((size_t)b << 12);
  for (int k = t; k < 4096; k += 256) {
    const float x = xr[k];
#pragma unroll
    for (int c = 0; c < 10; ++c) acc[c] += x * Wc[c * 4096 + k];
  }
#pragma unroll
  for (int c = 0; c < 10; ++c)
    for (int off = 32; off; off >>= 1) acc[c] += __shfl_xor(acc[c], off);
  if (lane == 0)
#pragma unroll
    for (int c = 0; c < 10; ++c) red[w][c] = acc[c];
  __syncthreads();
  if (t == 0) {
    float lg[10], ex[10];
    float m = -1e30f;
#pragma unroll
    for (int c = 0; c < 10; ++c) {
      lg[c] = red[0][c] + red[1][c] + red[2][c] + red[3][c] + bc[c];
      m = fmaxf(m, lg[c]);
    }
    float s = 0.f;
#pragma unroll
    for (int c = 0; c < 10; ++c) { ex[c] = expf(lg[c] - m); s += ex[c]; }
    const float inv = 1.f / s;
#pragma unroll
    for (int c = 0; c < 10; ++c) {
      cls[b * 10 + c] = lg[c];
      pred[b * 10 + c] = ex[c] * inv;
    }
  }
}

extern "C" void kernel_launch(void* const* d_in, const int* in_sizes, int n_in,
                              void* d_out, int out_size, void* d_ws, size_t ws_size,
                              hipStream_t stream) {
  (void)in_sizes; (void)n_in; (void)out_size; (void)ws_size;
  const float* X  = (const float*)d_in[0];
  const float* W0 = (const float*)d_in[1];
  const float* W  = (const float*)d_in[2];
  const float* bb = (const float*)d_in[3];
  const float* Wc = (const float*)d_in[4];
  const float* bc = (const float*)d_in[5];

  float* out_pred  = (float*)d_out;
  float* out_cls   = out_pred + 2560;
  float* out_trans = out_pred + 5120;

  char* ws = (char*)d_ws;
  float* Xf   = (float*)(ws);                      // 4 MB
  u16*   part = (u16*)  (ws + (4ull << 20));       // 8 MB (4 bf16 split-K planes)
  float* u_g  = (float*)(ws + (36ull << 20));      // 1 MB
  float* v_g  = (float*)(ws + (37ull << 20));      // 1 MB
  float* s_g  = (float*)(ws + (38ull << 20));      // 256 KB
  u16*   Xfb  = (u16*)  (ws + (39ull << 20));      // 2 MB
  float* outL = (float*)(ws + (41ull << 20));      // 36 MB (9 layer planes)

  init_kernel<<<NB, 512, 0, stream>>>(X, u_g, v_g, s_g, Xf, Xfb);
  for (int i = 0; i <= 8; ++i) {
    const float* Wl = (i == 0) ? W0 : W + (size_t)(i - 1) * DD * DD;
    gemm_kernel<<<dim3(64, 2 * SPLIT_K), 512, 0, stream>>>(Xfb, Wl, part);
    update_kernel<<<NB, 512, 0, stream>>>(
        part, (i == 0) ? nullptr : (bb + (size_t)(i - 1) * DD),
        u_g, v_g, s_g, Xf, Xfb, outL, i);
  }
  pack_kernel<<<4096, 256, 0, stream>>>(outL, out_trans);
  classifier_kernel<<<NB, 256, 0, stream>>>(Xf, Wc, bc, out_pred, out_cls);
}